// Round 1
// baseline (41.720 us; speedup 1.0000x reference)
//
#include <hip/hip_runtime.h>

// Bidirectional minGRU scan, linear-domain.
// x: (16, 512, 4096) f32.  out: (16, 256, 4096) f32.
// Row r = b*256 + c.  c<128: forward scan on h=x[b,c,:], g=x[b,c+128,:].
// c>=128: backward (time-reversed) scan on h=x[b,256+j,:], g=x[b,384+j,:], j=c-128,
// output written at the same (reversed) time index -> equals flip(scan(flip)).
//
// Per block (256 threads): each thread owns 16 contiguous scan steps.
// Phase 1: compute per-step (c_t, v_t) = (sigmoid(-g), sigmoid(g)*h'), local affine
//          composition (C, V) of the 16 steps.
// Phase 2: Hillis-Steele inclusive scan of (C,V) across 256 threads in LDS.
// Phase 3: replay chunk from incoming state, float4 stores.

#define T_LEN 4096
#define CHUNK 16
#define NTHR 256

__global__ __launch_bounds__(NTHR) void mingru_bidir_kernel(
    const float* __restrict__ x, float* __restrict__ out) {
  const int row = blockIdx.x;          // [0, 16*256)
  const int b   = row >> 8;
  const int c   = row & 255;
  const int tid = threadIdx.x;
  const bool bwd = (c >= 128);
  const int j = c & 127;

  const float* __restrict__ hptr =
      x + ((size_t)b * 512 + (bwd ? 256 : 0) + j) * T_LEN;
  const float* __restrict__ gptr =
      x + ((size_t)b * 512 + (bwd ? 384 : 128) + j) * T_LEN;
  float* __restrict__ optr = out + ((size_t)b * 256 + c) * T_LEN;

  // Element index base within the row for this thread's chunk.
  // fwd: chunk covers t in [16*tid, 16*tid+15], scan order = increasing t.
  // bwd: chunk covers scan steps s in [16*tid, 16*tid+15] with t = 4095-s,
  //      i.e. t in [4080-16*tid, 4095-16*tid], scan order = decreasing t.
  const int t0 = bwd ? (T_LEN - CHUNK - (tid << 4)) : (tid << 4);

  float cc[CHUNK], vv[CHUNK];  // per-step (coeff, value) in increasing-t order

  #pragma unroll
  for (int q = 0; q < 4; ++q) {
    const float4 h4 = *reinterpret_cast<const float4*>(hptr + t0 + 4 * q);
    const float4 g4 = *reinterpret_cast<const float4*>(gptr + t0 + 4 * q);
    const float hs[4] = {h4.x, h4.y, h4.z, h4.w};
    const float gs[4] = {g4.x, g4.y, g4.z, g4.w};
    #pragma unroll
    for (int r = 0; r < 4; ++r) {
      const int e = 4 * q + r;
      const float h = hs[r];
      const float g = gs[r];
      // h' = copysign(max(|h|, EPS), h)  (h==0 -> +EPS, matches reference)
      const float ah = fmaxf(fabsf(h), 1e-6f);
      const float hp = (h < 0.0f) ? -ah : ah;
      // stable sigmoid pair: e = exp(-|g|), inv = 1/(1+e)
      const float eg  = __expf(-fabsf(g));
      const float inv = 1.0f / (1.0f + eg);
      const float sg  = (g >= 0.0f) ? inv : eg * inv;  // sigmoid(g)
      const float co  = (g >= 0.0f) ? eg * inv : inv;  // sigmoid(-g)
      cc[e] = co;
      vv[e] = sg * hp;
    }
  }

  // For backward rows, flip register arrays into scan order (uniform branch,
  // constant indices only -> stays in registers).
  if (bwd) {
    #pragma unroll
    for (int e = 0; e < CHUNK / 2; ++e) {
      float t1 = cc[e]; cc[e] = cc[CHUNK - 1 - e]; cc[CHUNK - 1 - e] = t1;
      float t2 = vv[e]; vv[e] = vv[CHUNK - 1 - e]; vv[CHUNK - 1 - e] = t2;
    }
  }

  // Phase 1: local composition of the 16 affine steps (applied in order):
  // out = C*x + V after the whole chunk.
  float C = cc[0], V = vv[0];
  #pragma unroll
  for (int e = 1; e < CHUNK; ++e) {
    V = cc[e] * V + vv[e];
    C = C * cc[e];
  }

  // Phase 2: inclusive Hillis-Steele scan of (C,V) across the block.
  __shared__ float sC[NTHR], sV[NTHR];
  sC[tid] = C; sV[tid] = V;
  __syncthreads();
  #pragma unroll
  for (int off = 1; off < NTHR; off <<= 1) {
    float pc = 1.0f, pv = 0.0f;
    if (tid >= off) { pc = sC[tid - off]; pv = sV[tid - off]; }
    __syncthreads();
    if (tid >= off) {
      V = C * pv + V;   // compose: this-chunk after prev-chunks
      C = C * pc;
      sC[tid] = C; sV[tid] = V;
    }
    __syncthreads();
  }
  const float incoming = (tid == 0) ? 0.0f : sV[tid - 1];

  // Phase 3: replay chunk from incoming state; vv becomes the outputs.
  float st = incoming;
  #pragma unroll
  for (int e = 0; e < CHUNK; ++e) {
    st = cc[e] * st + vv[e];
    vv[e] = st;
  }

  // Back to increasing-t order for stores.
  if (bwd) {
    #pragma unroll
    for (int e = 0; e < CHUNK / 2; ++e) {
      float t2 = vv[e]; vv[e] = vv[CHUNK - 1 - e]; vv[CHUNK - 1 - e] = t2;
    }
  }

  #pragma unroll
  for (int q = 0; q < 4; ++q) {
    *reinterpret_cast<float4*>(optr + t0 + 4 * q) =
        make_float4(vv[4 * q], vv[4 * q + 1], vv[4 * q + 2], vv[4 * q + 3]);
  }
}

extern "C" void kernel_launch(void* const* d_in, const int* in_sizes, int n_in,
                              void* d_out, int out_size, void* d_ws, size_t ws_size,
                              hipStream_t stream) {
  const float* x = (const float*)d_in[0];
  float* out = (float*)d_out;
  const int rows = 16 * 256;  // one block per output row
  mingru_bidir_kernel<<<rows, NTHR, 0, stream>>>(x, out);
}